// Round 2
// baseline (1763.092 us; speedup 1.0000x reference)
//
#include <hip/hip_runtime.h>
#include <hip/hip_bf16.h>

#define NN 100000
#define EE 1600000
#define IND 128
#define HD 128
#define EM 64
#define KC 100
#define BN_EPS 1e-5f
#define BN_ROWS 256

// ---------------- degree / normalization ----------------
__global__ void k_deg_init(float* __restrict__ deg){
  int i = blockIdx.x*blockDim.x + threadIdx.x;
  if (i < NN) deg[i] = 1.0f;            // self loop counts once
}

__global__ void k_deg_acc(const int* __restrict__ ei, float* __restrict__ deg){
  int e = blockIdx.x*blockDim.x + threadIdx.x;
  if (e < EE) atomicAdd(&deg[ei[EE + e]], 1.0f);   // dst row of edge_index
}

__global__ void k_deg_rsqrt(float* __restrict__ deg){
  int i = blockIdx.x*blockDim.x + threadIdx.x;
  if (i < NN) deg[i] = rsqrtf(deg[i]);  // deg >= 1 always (self loops)
}

// ---------------- GEMM1: h1 = x @ W1 (fp32) ----------------
__global__ void k_gemm1(const float* __restrict__ x,
                        const float* __restrict__ W1,
                        float* __restrict__ h1){
  __shared__ float xs[IND];
  int row = blockIdx.x;
  int j = threadIdx.x;                  // 128 threads
  xs[j] = x[(size_t)row*IND + j];
  __syncthreads();
  float acc = 0.f;
  #pragma unroll 16
  for (int k = 0; k < IND; ++k)
    acc += xs[k] * W1[k*HD + j];        // lanes read contiguous 4B -> coalesced
  h1[(size_t)row*HD + j] = acc;
}

// ---------------- GCN1 scatter: hg[dst] += h1[src]*norm, self loop + b1 ----------------
__global__ void k_self1(const float* __restrict__ h1, const float* __restrict__ dis,
                        const float* __restrict__ b1, float* __restrict__ hg){
  int idx = blockIdx.x*blockDim.x + threadIdx.x;
  if (idx < NN*HD){
    int n = idx >> 7;
    float d = dis[n];
    hg[idx] = h1[idx]*d*d + b1[idx & (HD-1)];
  }
}

__global__ void k_scat1(const int* __restrict__ ei, const float* __restrict__ dis,
                        const float* __restrict__ h1, float* __restrict__ hg){
  int gid = blockIdx.x*blockDim.x + threadIdx.x;
  int e = gid >> 6;                      // one wave per edge
  if (e >= EE) return;
  int lane = gid & 63;
  int s = ei[e], d = ei[EE + e];
  float nm = dis[s]*dis[d];
  float v0 = h1[(size_t)s*HD + lane] * nm;
  float v1 = h1[(size_t)s*HD + 64 + lane] * nm;
  atomicAdd(&hg[(size_t)d*HD + lane], v0);
  atomicAdd(&hg[(size_t)d*HD + 64 + lane], v1);
}

// ---------------- BatchNorm (training stats) + ReLU ----------------
__global__ void k_stats_zero(float* __restrict__ sums, float* __restrict__ sumsq){
  int i = threadIdx.x;
  if (i < HD){ sums[i] = 0.f; sumsq[i] = 0.f; }
}

__global__ void k_bn_stats(const float* __restrict__ hg, float* __restrict__ sums,
                           float* __restrict__ sumsq){
  int j = threadIdx.x;                   // 128 threads = one column each
  int r0 = blockIdx.x * BN_ROWS;
  int r1 = min(r0 + BN_ROWS, NN);
  float s = 0.f, q = 0.f;
  for (int r = r0; r < r1; ++r){
    float v = hg[(size_t)r*HD + j];
    s += v; q += v*v;
  }
  atomicAdd(&sums[j], s);
  atomicAdd(&sumsq[j], q);
}

__global__ void k_bn_apply(float* __restrict__ hg, const float* __restrict__ sums,
                           const float* __restrict__ sumsq,
                           const float* __restrict__ gamma,
                           const float* __restrict__ beta){
  int idx = blockIdx.x*blockDim.x + threadIdx.x;
  if (idx < NN*HD){
    int j = idx & (HD-1);
    const float invN = 1.0f/(float)NN;
    float mu  = sums[j]*invN;
    float var = sumsq[j]*invN - mu*mu;
    float v = (hg[idx]-mu)*rsqrtf(var+BN_EPS)*gamma[j] + beta[j];
    hg[idx] = fmaxf(v, 0.f);
  }
}

// ---------------- GEMM2: h2 = h @ W2 ----------------
__global__ void k_gemm2(const float* __restrict__ hg, const float* __restrict__ W2,
                        float* __restrict__ h2){
  __shared__ float hs[4][HD];
  int w = threadIdx.x >> 6;
  int lane = threadIdx.x & 63;
  int row = blockIdx.x*4 + w;
  if (row < NN){
    hs[w][lane]      = hg[(size_t)row*HD + lane];
    hs[w][lane + 64] = hg[(size_t)row*HD + 64 + lane];
  }
  __syncthreads();
  if (row >= NN) return;
  float acc = 0.f;
  #pragma unroll 16
  for (int k = 0; k < HD; ++k)
    acc += hs[w][k] * W2[k*EM + lane];
  h2[(size_t)row*EM + lane] = acc;
}

// ---------------- GCN2 scatter ----------------
__global__ void k_self2(const float* __restrict__ h2, const float* __restrict__ dis,
                        float* __restrict__ embf){
  int idx = blockIdx.x*blockDim.x + threadIdx.x;
  if (idx < NN*EM){
    int n = idx >> 6;
    float d = dis[n];
    embf[idx] = h2[idx]*d*d;
  }
}

__global__ void k_scat2(const int* __restrict__ ei, const float* __restrict__ dis,
                        const float* __restrict__ h2, float* __restrict__ embf){
  int gid = blockIdx.x*blockDim.x + threadIdx.x;
  int e = gid >> 6;                      // one wave per edge, 1 feat/lane
  if (e >= EE) return;
  int lane = gid & 63;
  int s = ei[e], d = ei[EE + e];
  float nm = dis[s]*dis[d];
  atomicAdd(&embf[(size_t)d*EM + lane], h2[(size_t)s*EM + lane]*nm);
}

// ---------------- emb output (bias + store) ----------------
__global__ void k_emb_out(float* __restrict__ embf, const float* __restrict__ b2v,
                          float* __restrict__ out){
  int idx = blockIdx.x*blockDim.x + threadIdx.x;
  if (idx < NN*EM){
    float v = embf[idx] + b2v[idx & (EM-1)];
    embf[idx] = v;
    out[idx] = v;
  }
}

// ---------------- logits + softmax ----------------
__global__ void k_softmax(const float* __restrict__ embf,
                          const float* __restrict__ centers,
                          const float* __restrict__ temp,
                          float* __restrict__ out){
  __shared__ float cs[KC][EM+1];         // +1 pad: bank=(lane+k)%32, 2-way = free
  __shared__ float er[4][EM];
  for (int idx = threadIdx.x; idx < KC*EM; idx += blockDim.x)
    cs[idx>>6][idx&63] = centers[idx];
  int w = threadIdx.x >> 6;
  int lane = threadIdx.x & 63;
  int row = blockIdx.x*4 + w;            // one wave per node row
  if (row < NN) er[w][lane] = embf[(size_t)row*EM + lane];
  __syncthreads();
  if (row >= NN) return;

  float invT = 1.0f / temp[0];
  int c1 = (lane < KC-64) ? (lane + 64) : (KC-1);
  float a0 = 0.f, a1 = 0.f;
  #pragma unroll
  for (int k = 0; k < EM; ++k){
    float ev = er[w][k];
    a0 += ev * cs[lane][k];
    a1 += ev * cs[c1][k];
  }
  float lg0 = a0 * invT;
  float lg1 = (lane < KC-64) ? a1 * invT : -1e30f;
  float m = fmaxf(lg0, lg1);
  #pragma unroll
  for (int off = 32; off > 0; off >>= 1) m = fmaxf(m, __shfl_xor(m, off));
  float e0 = __expf(lg0 - m);
  float e1 = (lane < KC-64) ? __expf(lg1 - m) : 0.f;
  float ssum = e0 + e1;
  #pragma unroll
  for (int off = 32; off > 0; off >>= 1) ssum += __shfl_xor(ssum, off);
  float inv = 1.0f / ssum;

  float* orow = out + (size_t)NN*EM + (size_t)row*KC;
  orow[lane] = e0 * inv;
  if (lane < KC-64) orow[64 + lane] = e1 * inv;
}

// ---------------- launch ----------------
extern "C" void kernel_launch(void* const* d_in, const int* in_sizes, int n_in,
                              void* d_out, int out_size, void* d_ws, size_t ws_size,
                              hipStream_t stream){
  const float* x      = (const float*)d_in[0];
  const int*   ei     = (const int*)d_in[1];
  const float* W1     = (const float*)d_in[2];
  const float* b1     = (const float*)d_in[3];
  const float* gamma  = (const float*)d_in[4];
  const float* beta   = (const float*)d_in[5];
  const float* W2     = (const float*)d_in[6];
  const float* b2v    = (const float*)d_in[7];
  const float* ctr    = (const float*)d_in[8];
  const float* temp   = (const float*)d_in[9];
  float* out = (float*)d_out;

  // ws layout (floats): dis[NN] | bufA[NN*HD] | bufB[NN*HD] | sums[HD] | sumsq[HD]
  // bufA holds h1; after h1 dies it is reused as h2[NN*EM] | embf[NN*EM].
  float* ws    = (float*)d_ws;
  float* dis   = ws;
  float* bufA  = dis + NN;
  float* bufB  = bufA + (size_t)NN*HD;
  float* sums  = bufB + (size_t)NN*HD;
  float* sumsq = sums + HD;

  float* h1   = bufA;
  float* hg   = bufB;
  float* h2   = bufA;
  float* embf = bufA + (size_t)NN*EM;

  k_deg_init <<<(NN+255)/256, 256, 0, stream>>>(dis);
  k_deg_acc  <<<(EE+255)/256, 256, 0, stream>>>(ei, dis);
  k_deg_rsqrt<<<(NN+255)/256, 256, 0, stream>>>(dis);

  k_gemm1<<<NN, 128, 0, stream>>>(x, W1, h1);
  k_self1<<<(NN*HD+255)/256, 256, 0, stream>>>(h1, dis, b1, hg);
  k_scat1<<<(EE*64)/256, 256, 0, stream>>>(ei, dis, h1, hg);

  k_stats_zero<<<1, 128, 0, stream>>>(sums, sumsq);
  k_bn_stats<<<(NN+BN_ROWS-1)/BN_ROWS, 128, 0, stream>>>(hg, sums, sumsq);
  k_bn_apply<<<(NN*HD+255)/256, 256, 0, stream>>>(hg, sums, sumsq, gamma, beta);

  k_gemm2<<<(NN+3)/4, 256, 0, stream>>>(hg, W2, h2);
  k_self2<<<(NN*EM+255)/256, 256, 0, stream>>>(h2, dis, embf);
  k_scat2<<<(EE*64)/256, 256, 0, stream>>>(ei, dis, h2, embf);

  k_emb_out<<<(NN*EM+255)/256, 256, 0, stream>>>(embf, b2v, out);
  k_softmax<<<(NN+3)/4, 256, 0, stream>>>(embf, ctr, temp, out);
}

// Round 3
// 1246.476 us; speedup vs baseline: 1.4145x; 1.4145x over previous
//
#include <hip/hip_runtime.h>
#include <hip/hip_bf16.h>

#define NN 100000
#define EE 1600000
#define IND 128
#define HD 128
#define EM 64
#define KC 100
#define BN_EPS 1e-5f
#define BN_ROWS 256
#define CHUNK 1024
#define NB ((NN + CHUNK - 1) / CHUNK)   // 98 scan blocks

// ---------------- histogram of dst (in-degree, excl self loop) ----------------
__global__ void k_hist_zero(int* __restrict__ cnt){
  int i = blockIdx.x*blockDim.x + threadIdx.x;
  if (i < NN) cnt[i] = 0;
}

__global__ void k_hist(const int* __restrict__ ei, int* __restrict__ cnt){
  int e = blockIdx.x*blockDim.x + threadIdx.x;
  if (e < EE) atomicAdd(&cnt[ei[EE + e]], 1);
}

__global__ void k_dis(const int* __restrict__ cnt, float* __restrict__ dis){
  int i = blockIdx.x*blockDim.x + threadIdx.x;
  if (i < NN) dis[i] = rsqrtf((float)cnt[i] + 1.0f);   // +1 self loop
}

// ---------------- 3-level exclusive scan: rowptr = exscan(cnt) ----------------
__global__ void k_scan1(const int* __restrict__ cnt, int* __restrict__ rowptr,
                        int* __restrict__ bsum){
  __shared__ int ls[256];
  int b = blockIdx.x, t = threadIdx.x;
  int base = b*CHUNK + t*4;
  int v0 = (base+0 < NN) ? cnt[base+0] : 0;
  int v1 = (base+1 < NN) ? cnt[base+1] : 0;
  int v2 = (base+2 < NN) ? cnt[base+2] : 0;
  int v3 = (base+3 < NN) ? cnt[base+3] : 0;
  int s = v0+v1+v2+v3;
  ls[t] = s; __syncthreads();
  #pragma unroll
  for (int off = 1; off < 256; off <<= 1){
    int x = (t >= off) ? ls[t-off] : 0;
    __syncthreads();
    ls[t] += x;
    __syncthreads();
  }
  int run = ls[t] - s;                   // exclusive prefix of this thread
  if (t == 255) bsum[b] = ls[255];
  if (base+0 < NN) rowptr[base+0] = run; run += v0;
  if (base+1 < NN) rowptr[base+1] = run; run += v1;
  if (base+2 < NN) rowptr[base+2] = run; run += v2;
  if (base+3 < NN) rowptr[base+3] = run;
}

__global__ void k_scan2(int* __restrict__ bsum){
  __shared__ int ls[128];
  int t = threadIdx.x;
  int v = (t < NB) ? bsum[t] : 0;
  ls[t] = v; __syncthreads();
  #pragma unroll
  for (int off = 1; off < 128; off <<= 1){
    int x = (t >= off) ? ls[t-off] : 0;
    __syncthreads();
    ls[t] += x;
    __syncthreads();
  }
  if (t < NB) bsum[t] = ls[t] - v;       // exclusive
}

__global__ void k_scan3(int* __restrict__ rowptr, const int* __restrict__ bsum,
                        int* __restrict__ rptr2){
  int i = blockIdx.x*blockDim.x + threadIdx.x;
  if (i < NN){
    int v = rowptr[i] + bsum[i / CHUNK];
    rowptr[i] = v;
    rptr2[i]  = v;
  }
  if (i == 0) rowptr[NN] = EE;
}

// ---------------- CSR fill (order within a node arbitrary; fp32 sum tol ok) ---
__global__ void k_fill(const int* __restrict__ ei, int* __restrict__ rptr2,
                       int* __restrict__ esrc){
  int e = blockIdx.x*blockDim.x + threadIdx.x;
  if (e < EE){
    int s = ei[e], d = ei[EE + e];
    int pos = atomicAdd(&rptr2[d], 1);
    esrc[pos] = s;
  }
}

// ---------------- GEMM1: h1 = x @ W1 (fp32) ----------------
__global__ void k_gemm1(const float* __restrict__ x,
                        const float* __restrict__ W1,
                        float* __restrict__ h1){
  __shared__ float xs[IND];
  int row = blockIdx.x;
  int j = threadIdx.x;                  // 128 threads
  xs[j] = x[(size_t)row*IND + j];
  __syncthreads();
  float acc = 0.f;
  #pragma unroll 16
  for (int k = 0; k < IND; ++k)
    acc += xs[k] * W1[k*HD + j];
  h1[(size_t)row*HD + j] = acc;
}

// ---------------- GCN1 aggregation as gather: one wave per dst node -----------
__global__ __launch_bounds__(256) void k_gather1(
    const int* __restrict__ rowptr, const int* __restrict__ esrc,
    const float* __restrict__ dis, const float* __restrict__ h1,
    const float* __restrict__ b1, float* __restrict__ hg){
  int w = threadIdx.x >> 6, lane = threadIdx.x & 63;
  int d = blockIdx.x*4 + w;              // grid exact: NN % 4 == 0
  float dd = dis[d];
  const float* hr = h1 + (size_t)d*HD;
  float a0 = hr[lane]      * dd*dd;      // self loop
  float a1 = hr[64 + lane] * dd*dd;
  int p0 = rowptr[d], p1 = rowptr[d+1];
  int s = 0; float nm = 0.f;
  if (p0 < p1){ s = esrc[p0]; nm = dis[s]*dd; }
  for (int p = p0; p < p1; ++p){
    int cs = s; float cn = nm;
    if (p+1 < p1){ s = esrc[p+1]; nm = dis[s]*dd; }  // prefetch next
    const float* r = h1 + (size_t)cs*HD;
    a0 += r[lane]      * cn;
    a1 += r[64 + lane] * cn;
  }
  hg[(size_t)d*HD + lane]      = a0 + b1[lane];
  hg[(size_t)d*HD + 64 + lane] = a1 + b1[64 + lane];
}

// ---------------- BatchNorm (training stats) + ReLU ----------------
__global__ void k_stats_zero(float* __restrict__ sums, float* __restrict__ sumsq){
  int i = threadIdx.x;
  if (i < HD){ sums[i] = 0.f; sumsq[i] = 0.f; }
}

__global__ void k_bn_stats(const float* __restrict__ hg, float* __restrict__ sums,
                           float* __restrict__ sumsq){
  int j = threadIdx.x;
  int r0 = blockIdx.x * BN_ROWS;
  int r1 = min(r0 + BN_ROWS, NN);
  float s = 0.f, q = 0.f;
  for (int r = r0; r < r1; ++r){
    float v = hg[(size_t)r*HD + j];
    s += v; q += v*v;
  }
  atomicAdd(&sums[j], s);
  atomicAdd(&sumsq[j], q);
}

__global__ void k_bn_apply(float* __restrict__ hg, const float* __restrict__ sums,
                           const float* __restrict__ sumsq,
                           const float* __restrict__ gamma,
                           const float* __restrict__ beta){
  int idx = blockIdx.x*blockDim.x + threadIdx.x;
  if (idx < NN*HD){
    int j = idx & (HD-1);
    const float invN = 1.0f/(float)NN;
    float mu  = sums[j]*invN;
    float var = sumsq[j]*invN - mu*mu;
    float v = (hg[idx]-mu)*rsqrtf(var+BN_EPS)*gamma[j] + beta[j];
    hg[idx] = fmaxf(v, 0.f);
  }
}

// ---------------- GEMM2: h2 = h @ W2 ----------------
__global__ void k_gemm2(const float* __restrict__ hg, const float* __restrict__ W2,
                        float* __restrict__ h2){
  __shared__ float hs[4][HD];
  int w = threadIdx.x >> 6;
  int lane = threadIdx.x & 63;
  int row = blockIdx.x*4 + w;
  hs[w][lane]      = hg[(size_t)row*HD + lane];
  hs[w][lane + 64] = hg[(size_t)row*HD + 64 + lane];
  __syncthreads();
  float acc = 0.f;
  #pragma unroll 16
  for (int k = 0; k < HD; ++k)
    acc += hs[w][k] * W2[k*EM + lane];
  h2[(size_t)row*EM + lane] = acc;
}

// ---------------- GCN2 aggregation gather + bias + emb output -----------------
__global__ __launch_bounds__(256) void k_gather2(
    const int* __restrict__ rowptr, const int* __restrict__ esrc,
    const float* __restrict__ dis, const float* __restrict__ h2,
    const float* __restrict__ b2v, float* __restrict__ embf,
    float* __restrict__ out){
  int w = threadIdx.x >> 6, lane = threadIdx.x & 63;
  int d = blockIdx.x*4 + w;
  float dd = dis[d];
  float a = h2[(size_t)d*EM + lane] * dd*dd;   // self loop
  int p0 = rowptr[d], p1 = rowptr[d+1];
  int s = 0; float nm = 0.f;
  if (p0 < p1){ s = esrc[p0]; nm = dis[s]*dd; }
  for (int p = p0; p < p1; ++p){
    int cs = s; float cn = nm;
    if (p+1 < p1){ s = esrc[p+1]; nm = dis[s]*dd; }
    a += h2[(size_t)cs*EM + lane] * cn;
  }
  float v = a + b2v[lane];
  embf[(size_t)d*EM + lane] = v;
  out [(size_t)d*EM + lane] = v;
}

// ---------------- logits + softmax ----------------
__global__ void k_softmax(const float* __restrict__ embf,
                          const float* __restrict__ centers,
                          const float* __restrict__ temp,
                          float* __restrict__ out){
  __shared__ float cs[KC][EM+1];
  __shared__ float er[4][EM];
  for (int idx = threadIdx.x; idx < KC*EM; idx += blockDim.x)
    cs[idx>>6][idx&63] = centers[idx];
  int w = threadIdx.x >> 6;
  int lane = threadIdx.x & 63;
  int row = blockIdx.x*4 + w;
  er[w][lane] = embf[(size_t)row*EM + lane];
  __syncthreads();

  float invT = 1.0f / temp[0];
  int c1 = (lane < KC-64) ? (lane + 64) : (KC-1);
  float a0 = 0.f, a1 = 0.f;
  #pragma unroll
  for (int k = 0; k < EM; ++k){
    float ev = er[w][k];
    a0 += ev * cs[lane][k];
    a1 += ev * cs[c1][k];
  }
  float lg0 = a0 * invT;
  float lg1 = (lane < KC-64) ? a1 * invT : -1e30f;
  float m = fmaxf(lg0, lg1);
  #pragma unroll
  for (int off = 32; off > 0; off >>= 1) m = fmaxf(m, __shfl_xor(m, off));
  float e0 = __expf(lg0 - m);
  float e1 = (lane < KC-64) ? __expf(lg1 - m) : 0.f;
  float ssum = e0 + e1;
  #pragma unroll
  for (int off = 32; off > 0; off >>= 1) ssum += __shfl_xor(ssum, off);
  float inv = 1.0f / ssum;

  float* orow = out + (size_t)NN*EM + (size_t)row*KC;
  orow[lane] = e0 * inv;
  if (lane < KC-64) orow[64 + lane] = e1 * inv;
}

// ---------------- launch ----------------
extern "C" void kernel_launch(void* const* d_in, const int* in_sizes, int n_in,
                              void* d_out, int out_size, void* d_ws, size_t ws_size,
                              hipStream_t stream){
  const float* x      = (const float*)d_in[0];
  const int*   ei     = (const int*)d_in[1];
  const float* W1     = (const float*)d_in[2];
  const float* b1     = (const float*)d_in[3];
  const float* gamma  = (const float*)d_in[4];
  const float* beta   = (const float*)d_in[5];
  const float* W2     = (const float*)d_in[6];
  const float* b2v    = (const float*)d_in[7];
  const float* ctr    = (const float*)d_in[8];
  const float* temp   = (const float*)d_in[9];
  float* out = (float*)d_out;

  // ws layout: dis[NN] f | bufA[NN*HD] f | bufB[NN*HD] f | sums/sumsq[HD] f |
  //            cnt[NN] i | rowptr[NN+1] i | rptr2[NN] i | bsum[128] i | esrc[EE] i
  float* ws     = (float*)d_ws;
  float* dis    = ws;
  float* bufA   = dis + NN;
  float* bufB   = bufA + (size_t)NN*HD;
  float* sums   = bufB + (size_t)NN*HD;
  float* sumsq  = sums + HD;
  int*   cnt    = (int*)(sumsq + HD);
  int*   rowptr = cnt + NN;
  int*   rptr2  = rowptr + NN + 1;
  int*   bsum   = rptr2 + NN;
  int*   esrc   = bsum + 128;

  float* h1   = bufA;
  float* hg   = bufB;
  float* h2   = bufA;                      // reuse after h1 dies
  float* embf = bufA + (size_t)NN*EM;

  k_hist_zero<<<(NN+255)/256, 256, 0, stream>>>(cnt);
  k_hist     <<<(EE+255)/256, 256, 0, stream>>>(ei, cnt);
  k_dis      <<<(NN+255)/256, 256, 0, stream>>>(cnt, dis);
  k_scan1    <<<NB, 256, 0, stream>>>(cnt, rowptr, bsum);
  k_scan2    <<<1, 128, 0, stream>>>(bsum);
  k_scan3    <<<(NN+255)/256, 256, 0, stream>>>(rowptr, bsum, rptr2);
  k_fill     <<<(EE+255)/256, 256, 0, stream>>>(ei, rptr2, esrc);

  k_gemm1  <<<NN, 128, 0, stream>>>(x, W1, h1);
  k_gather1<<<NN/4, 256, 0, stream>>>(rowptr, esrc, dis, h1, b1, hg);

  k_stats_zero<<<1, 128, 0, stream>>>(sums, sumsq);
  k_bn_stats<<<(NN+BN_ROWS-1)/BN_ROWS, 128, 0, stream>>>(hg, sums, sumsq);
  k_bn_apply<<<(NN*HD+255)/256, 256, 0, stream>>>(hg, sums, sumsq, gamma, beta);

  k_gemm2  <<<NN/4, 256, 0, stream>>>(hg, W2, h2);
  k_gather2<<<NN/4, 256, 0, stream>>>(rowptr, esrc, dis, h2, b2v, embf, out);

  k_softmax<<<NN/4, 256, 0, stream>>>(embf, ctr, temp, out);
}

// Round 4
// 778.889 us; speedup vs baseline: 2.2636x; 1.6003x over previous
//
#include <hip/hip_runtime.h>
#include <hip/hip_bf16.h>

#define NN 100000
#define EE 1600000
#define IND 128
#define HD 128
#define EM 64
#define KC 100
#define BN_EPS 1e-5f
#define BN_ROWS 128
#define CHUNK 1024
#define NB ((NN + CHUNK - 1) / CHUNK)   // 98 scan blocks

// ---------------- histogram of dst (in-degree, excl self loop) ----------------
__global__ void k_hist_zero(int* __restrict__ cnt){
  int i = blockIdx.x*blockDim.x + threadIdx.x;
  if (i < NN) cnt[i] = 0;
}

__global__ void k_hist(const int* __restrict__ ei, int* __restrict__ cnt){
  int e = blockIdx.x*blockDim.x + threadIdx.x;
  if (e < EE) atomicAdd(&cnt[ei[EE + e]], 1);
}

__global__ void k_dis(const int* __restrict__ cnt, float* __restrict__ dis){
  int i = blockIdx.x*blockDim.x + threadIdx.x;
  if (i < NN) dis[i] = rsqrtf((float)cnt[i] + 1.0f);   // +1 self loop
}

// ---------------- 3-level exclusive scan: rowptr = exscan(cnt) ----------------
__global__ void k_scan1(const int* __restrict__ cnt, int* __restrict__ rowptr,
                        int* __restrict__ bsum){
  __shared__ int ls[256];
  int b = blockIdx.x, t = threadIdx.x;
  int base = b*CHUNK + t*4;
  int v0 = (base+0 < NN) ? cnt[base+0] : 0;
  int v1 = (base+1 < NN) ? cnt[base+1] : 0;
  int v2 = (base+2 < NN) ? cnt[base+2] : 0;
  int v3 = (base+3 < NN) ? cnt[base+3] : 0;
  int s = v0+v1+v2+v3;
  ls[t] = s; __syncthreads();
  #pragma unroll
  for (int off = 1; off < 256; off <<= 1){
    int x = (t >= off) ? ls[t-off] : 0;
    __syncthreads();
    ls[t] += x;
    __syncthreads();
  }
  int run = ls[t] - s;
  if (t == 255) bsum[b] = ls[255];
  if (base+0 < NN) rowptr[base+0] = run; run += v0;
  if (base+1 < NN) rowptr[base+1] = run; run += v1;
  if (base+2 < NN) rowptr[base+2] = run; run += v2;
  if (base+3 < NN) rowptr[base+3] = run;
}

__global__ void k_scan2(int* __restrict__ bsum){
  __shared__ int ls[128];
  int t = threadIdx.x;
  int v = (t < NB) ? bsum[t] : 0;
  ls[t] = v; __syncthreads();
  #pragma unroll
  for (int off = 1; off < 128; off <<= 1){
    int x = (t >= off) ? ls[t-off] : 0;
    __syncthreads();
    ls[t] += x;
    __syncthreads();
  }
  if (t < NB) bsum[t] = ls[t] - v;
}

__global__ void k_scan3(int* __restrict__ rowptr, const int* __restrict__ bsum,
                        int* __restrict__ rptr2){
  int i = blockIdx.x*blockDim.x + threadIdx.x;
  if (i < NN){
    int v = rowptr[i] + bsum[i / CHUNK];
    rowptr[i] = v;
    rptr2[i]  = v;
  }
  if (i == 0) rowptr[NN] = EE;
}

// ---------------- CSR fill ----------------
__global__ void k_fill(const int* __restrict__ ei, int* __restrict__ rptr2,
                       int* __restrict__ esrc){
  int e = blockIdx.x*blockDim.x + threadIdx.x;
  if (e < EE){
    int s = ei[e], d = ei[EE + e];
    int pos = atomicAdd(&rptr2[d], 1);
    esrc[pos] = s;
  }
}

// ---------------- GEMM1: h1 = x @ W1, 64-row tile, 8x4 per thread -------------
__global__ __launch_bounds__(256) void k_gemm1(const float* __restrict__ x,
                                               const float* __restrict__ W1,
                                               float* __restrict__ h1){
  __shared__ float xs[64][IND];           // 32 KB
  int t = threadIdx.x;
  int rbase = blockIdx.x * 64;
  #pragma unroll
  for (int i = 0; i < 8; ++i){
    int flat = i*256 + t;                 // 0..2047
    int r = flat >> 5;
    int q = flat & 31;
    float4 v = make_float4(0.f,0.f,0.f,0.f);
    if (rbase + r < NN) v = *(const float4*)&x[(size_t)(rbase+r)*IND + q*4];
    *(float4*)&xs[r][q*4] = v;
  }
  __syncthreads();
  int c0 = (t & 31) * 4;                  // 4 consecutive cols
  int r0 = (t >> 5) * 8;                  // 8 rows
  float acc[8][4] = {};
  #pragma unroll 4
  for (int k4 = 0; k4 < IND/4; ++k4){
    float4 w0 = *(const float4*)&W1[(k4*4+0)*HD + c0];
    float4 w1 = *(const float4*)&W1[(k4*4+1)*HD + c0];
    float4 w2 = *(const float4*)&W1[(k4*4+2)*HD + c0];
    float4 w3 = *(const float4*)&W1[(k4*4+3)*HD + c0];
    #pragma unroll
    for (int g = 0; g < 8; ++g){
      float4 xv = *(const float4*)&xs[r0+g][k4*4];
      acc[g][0] += xv.x*w0.x + xv.y*w1.x + xv.z*w2.x + xv.w*w3.x;
      acc[g][1] += xv.x*w0.y + xv.y*w1.y + xv.z*w2.y + xv.w*w3.y;
      acc[g][2] += xv.x*w0.z + xv.y*w1.z + xv.z*w2.z + xv.w*w3.z;
      acc[g][3] += xv.x*w0.w + xv.y*w1.w + xv.z*w2.w + xv.w*w3.w;
    }
  }
  #pragma unroll
  for (int g = 0; g < 8; ++g){
    int r = rbase + r0 + g;
    if (r < NN) *(float4*)&h1[(size_t)r*HD + c0] = *(float4*)&acc[g][0];
  }
}

// ---------------- GCN1 gather: 1 wave/node, 2 edges per iter ------------------
__global__ __launch_bounds__(256) void k_gather1(
    const int* __restrict__ rowptr, const int* __restrict__ esrc,
    const float* __restrict__ dis, const float* __restrict__ h1,
    const float* __restrict__ b1, float* __restrict__ hg){
  int w = threadIdx.x >> 6, lane = threadIdx.x & 63;
  int d = blockIdx.x*4 + w;               // NN % 4 == 0
  int half = lane >> 5;                   // 0/1: which edge of the pair
  int q = lane & 31;                      // float4 chunk within 128-float row
  float dd = dis[d];
  float4 a = make_float4(0.f,0.f,0.f,0.f);
  if (half == 0){                         // self loop
    float4 v = *(const float4*)&h1[(size_t)d*HD + q*4];
    float s2 = dd*dd;
    a.x = v.x*s2; a.y = v.y*s2; a.z = v.z*s2; a.w = v.w*s2;
  }
  int p0 = rowptr[d], p1 = rowptr[d+1];
  for (int p = p0 + half; p < p1; p += 2){
    int s = esrc[p];                      // uniform within half-wave
    float nm = dis[s]*dd;
    float4 v = *(const float4*)&h1[(size_t)s*HD + q*4];
    a.x += v.x*nm; a.y += v.y*nm; a.z += v.z*nm; a.w += v.w*nm;
  }
  a.x += __shfl_xor(a.x, 32); a.y += __shfl_xor(a.y, 32);
  a.z += __shfl_xor(a.z, 32); a.w += __shfl_xor(a.w, 32);
  if (half == 0){
    float4 b = *(const float4*)&b1[q*4];
    a.x += b.x; a.y += b.y; a.z += b.z; a.w += b.w;
    *(float4*)&hg[(size_t)d*HD + q*4] = a;
  }
}

// ---------------- BatchNorm stats + coefficients ----------------
__global__ void k_stats_zero(float* __restrict__ sums, float* __restrict__ sumsq){
  int i = threadIdx.x;
  if (i < HD){ sums[i] = 0.f; sumsq[i] = 0.f; }
}

__global__ void k_bn_stats(const float* __restrict__ hg, float* __restrict__ sums,
                           float* __restrict__ sumsq){
  int j = threadIdx.x;
  int r0 = blockIdx.x * BN_ROWS;
  int r1 = min(r0 + BN_ROWS, NN);
  float s = 0.f, q = 0.f;
  for (int r = r0; r < r1; ++r){
    float v = hg[(size_t)r*HD + j];
    s += v; q += v*v;
  }
  atomicAdd(&sums[j], s);
  atomicAdd(&sumsq[j], q);
}

__global__ void k_bn_coef(const float* __restrict__ sums, const float* __restrict__ sumsq,
                          const float* __restrict__ gamma, const float* __restrict__ beta,
                          float* __restrict__ scale, float* __restrict__ shift){
  int j = threadIdx.x;                    // 128 threads
  const float invN = 1.0f/(float)NN;
  float mu  = sums[j]*invN;
  float var = sumsq[j]*invN - mu*mu;
  float sc  = gamma[j]*rsqrtf(var+BN_EPS);
  scale[j] = sc;
  shift[j] = beta[j] - mu*sc;
}

// ---------------- GEMM2: h2 = relu(bn(hg)) @ W2 (BN fused in staging) ---------
__global__ __launch_bounds__(256) void k_gemm2(const float* __restrict__ hg,
                                               const float* __restrict__ W2,
                                               const float* __restrict__ scale,
                                               const float* __restrict__ shift,
                                               float* __restrict__ h2){
  __shared__ float hs[64][HD];            // 32 KB
  int t = threadIdx.x;
  int rbase = blockIdx.x * 64;
  #pragma unroll
  for (int i = 0; i < 8; ++i){
    int flat = i*256 + t;
    int r = flat >> 5;
    int q = flat & 31;
    float4 v = make_float4(0.f,0.f,0.f,0.f);
    if (rbase + r < NN){
      v = *(const float4*)&hg[(size_t)(rbase+r)*HD + q*4];
      float4 sc = *(const float4*)&scale[q*4];
      float4 sh = *(const float4*)&shift[q*4];
      v.x = fmaxf(v.x*sc.x + sh.x, 0.f);
      v.y = fmaxf(v.y*sc.y + sh.y, 0.f);
      v.z = fmaxf(v.z*sc.z + sh.z, 0.f);
      v.w = fmaxf(v.w*sc.w + sh.w, 0.f);
    }
    *(float4*)&hs[r][q*4] = v;
  }
  __syncthreads();
  int c0 = (t & 15) * 4;                  // 4 consecutive of 64 cols
  int r0 = (t >> 4) * 4;                  // 4 rows
  float acc[4][4] = {};
  #pragma unroll 4
  for (int k4 = 0; k4 < HD/4; ++k4){
    float4 w0 = *(const float4*)&W2[(k4*4+0)*EM + c0];
    float4 w1 = *(const float4*)&W2[(k4*4+1)*EM + c0];
    float4 w2 = *(const float4*)&W2[(k4*4+2)*EM + c0];
    float4 w3 = *(const float4*)&W2[(k4*4+3)*EM + c0];
    #pragma unroll
    for (int g = 0; g < 4; ++g){
      float4 xv = *(const float4*)&hs[r0+g][k4*4];
      acc[g][0] += xv.x*w0.x + xv.y*w1.x + xv.z*w2.x + xv.w*w3.x;
      acc[g][1] += xv.x*w0.y + xv.y*w1.y + xv.z*w2.y + xv.w*w3.y;
      acc[g][2] += xv.x*w0.z + xv.y*w1.z + xv.z*w2.z + xv.w*w3.z;
      acc[g][3] += xv.x*w0.w + xv.y*w1.w + xv.z*w2.w + xv.w*w3.w;
    }
  }
  #pragma unroll
  for (int g = 0; g < 4; ++g){
    int r = rbase + r0 + g;
    if (r < NN) *(float4*)&h2[(size_t)r*EM + c0] = *(float4*)&acc[g][0];
  }
}

// ---------------- GCN2 gather: 1 wave/node, 4 edges per iter, + bias + out ----
__global__ __launch_bounds__(256) void k_gather2(
    const int* __restrict__ rowptr, const int* __restrict__ esrc,
    const float* __restrict__ dis, const float* __restrict__ h2,
    const float* __restrict__ b2v, float* __restrict__ embf,
    float* __restrict__ out){
  int w = threadIdx.x >> 6, lane = threadIdx.x & 63;
  int d = blockIdx.x*4 + w;
  int sub = lane >> 4;                    // 0..3: which edge of the quad
  int q = lane & 15;                      // float4 chunk within 64-float row
  float dd = dis[d];
  float4 a = make_float4(0.f,0.f,0.f,0.f);
  if (sub == 0){                          // self loop
    float4 v = *(const float4*)&h2[(size_t)d*EM + q*4];
    float s2 = dd*dd;
    a.x = v.x*s2; a.y = v.y*s2; a.z = v.z*s2; a.w = v.w*s2;
  }
  int p0 = rowptr[d], p1 = rowptr[d+1];
  for (int p = p0 + sub; p < p1; p += 4){
    int s = esrc[p];
    float nm = dis[s]*dd;
    float4 v = *(const float4*)&h2[(size_t)s*EM + q*4];
    a.x += v.x*nm; a.y += v.y*nm; a.z += v.z*nm; a.w += v.w*nm;
  }
  a.x += __shfl_xor(a.x, 32); a.y += __shfl_xor(a.y, 32);
  a.z += __shfl_xor(a.z, 32); a.w += __shfl_xor(a.w, 32);
  a.x += __shfl_xor(a.x, 16); a.y += __shfl_xor(a.y, 16);
  a.z += __shfl_xor(a.z, 16); a.w += __shfl_xor(a.w, 16);
  if (sub == 0){
    float4 b = *(const float4*)&b2v[q*4];
    a.x += b.x; a.y += b.y; a.z += b.z; a.w += b.w;
    *(float4*)&embf[(size_t)d*EM + q*4] = a;
    *(float4*)&out [(size_t)d*EM + q*4] = a;
  }
}

// ---------------- logits + softmax ----------------
__global__ void k_softmax(const float* __restrict__ embf,
                          const float* __restrict__ centers,
                          const float* __restrict__ temp,
                          float* __restrict__ out){
  __shared__ float cs[KC][EM+1];
  __shared__ float er[4][EM];
  for (int idx = threadIdx.x; idx < KC*EM; idx += blockDim.x)
    cs[idx>>6][idx&63] = centers[idx];
  int w = threadIdx.x >> 6;
  int lane = threadIdx.x & 63;
  int row = blockIdx.x*4 + w;
  er[w][lane] = embf[(size_t)row*EM + lane];
  __syncthreads();

  float invT = 1.0f / temp[0];
  int c1 = (lane < KC-64) ? (lane + 64) : (KC-1);
  float a0 = 0.f, a1 = 0.f;
  #pragma unroll
  for (int k = 0; k < EM; ++k){
    float ev = er[w][k];
    a0 += ev * cs[lane][k];
    a1 += ev * cs[c1][k];
  }
  float lg0 = a0 * invT;
  float lg1 = (lane < KC-64) ? a1 * invT : -1e30f;
  float m = fmaxf(lg0, lg1);
  #pragma unroll
  for (int off = 32; off > 0; off >>= 1) m = fmaxf(m, __shfl_xor(m, off));
  float e0 = __expf(lg0 - m);
  float e1 = (lane < KC-64) ? __expf(lg1 - m) : 0.f;
  float ssum = e0 + e1;
  #pragma unroll
  for (int off = 32; off > 0; off >>= 1) ssum += __shfl_xor(ssum, off);
  float inv = 1.0f / ssum;

  float* orow = out + (size_t)NN*EM + (size_t)row*KC;
  orow[lane] = e0 * inv;
  if (lane < KC-64) orow[64 + lane] = e1 * inv;
}

// ---------------- launch ----------------
extern "C" void kernel_launch(void* const* d_in, const int* in_sizes, int n_in,
                              void* d_out, int out_size, void* d_ws, size_t ws_size,
                              hipStream_t stream){
  const float* x      = (const float*)d_in[0];
  const int*   ei     = (const int*)d_in[1];
  const float* W1     = (const float*)d_in[2];
  const float* b1     = (const float*)d_in[3];
  const float* gamma  = (const float*)d_in[4];
  const float* beta   = (const float*)d_in[5];
  const float* W2     = (const float*)d_in[6];
  const float* b2v    = (const float*)d_in[7];
  const float* ctr    = (const float*)d_in[8];
  const float* temp   = (const float*)d_in[9];
  float* out = (float*)d_out;

  // ws: dis[NN] f | bufA[NN*HD] f | bufB[NN*HD] f | sums[HD] sumsq[HD] scale[HD] shift[HD] f |
  //     cnt[NN] i | rowptr[NN+1] i | rptr2[NN] i | bsum[128] i | esrc[EE] i
  float* ws     = (float*)d_ws;
  float* dis    = ws;
  float* bufA   = dis + NN;
  float* bufB   = bufA + (size_t)NN*HD;
  float* sums   = bufB + (size_t)NN*HD;
  float* sumsq  = sums + HD;
  float* scale  = sumsq + HD;
  float* shift  = scale + HD;
  int*   cnt    = (int*)(shift + HD);
  int*   rowptr = cnt + NN;
  int*   rptr2  = rowptr + NN + 1;
  int*   bsum   = rptr2 + NN;
  int*   esrc   = bsum + 128;

  float* h1   = bufA;
  float* hg   = bufB;
  float* h2   = bufA;                      // reuse after h1 dies
  float* embf = bufA + (size_t)NN*EM;

  k_hist_zero<<<(NN+255)/256, 256, 0, stream>>>(cnt);
  k_hist     <<<(EE+255)/256, 256, 0, stream>>>(ei, cnt);
  k_dis      <<<(NN+255)/256, 256, 0, stream>>>(cnt, dis);
  k_scan1    <<<NB, 256, 0, stream>>>(cnt, rowptr, bsum);
  k_scan2    <<<1, 128, 0, stream>>>(bsum);
  k_scan3    <<<(NN+255)/256, 256, 0, stream>>>(rowptr, bsum, rptr2);
  k_fill     <<<(EE+255)/256, 256, 0, stream>>>(ei, rptr2, esrc);

  k_gemm1  <<<(NN+63)/64, 256, 0, stream>>>(x, W1, h1);
  k_gather1<<<NN/4, 256, 0, stream>>>(rowptr, esrc, dis, h1, b1, hg);

  k_stats_zero<<<1, 128, 0, stream>>>(sums, sumsq);
  k_bn_stats<<<(NN+BN_ROWS-1)/BN_ROWS, 128, 0, stream>>>(hg, sums, sumsq);
  k_bn_coef <<<1, 128, 0, stream>>>(sums, sumsq, gamma, beta, scale, shift);

  k_gemm2  <<<(NN+63)/64, 256, 0, stream>>>(hg, W2, scale, shift, h2);
  k_gather2<<<NN/4, 256, 0, stream>>>(rowptr, esrc, dis, h2, b2v, embf, out);

  k_softmax<<<NN/4, 256, 0, stream>>>(embf, ctr, temp, out);
}

// Round 5
// 754.653 us; speedup vs baseline: 2.3363x; 1.0321x over previous
//
#include <hip/hip_runtime.h>
#include <hip/hip_bf16.h>

#define NN 100000
#define EE 1600000
#define IND 128
#define HD 128
#define EM 64
#define KC 100
#define BN_EPS 1e-5f
#define BN_ROWS 128
#define BKT 512
#define NBK ((NN + BKT - 1) / BKT)      // 196 buckets (dst >> 9)
#define SROWS 32                         // softmax rows per block

// ---------------- bucketed CSR build ----------------
__global__ void k_zero256(int* __restrict__ gcnt){
  int t = threadIdx.x;
  if (t < NBK) gcnt[t] = 0;
}

__global__ __launch_bounds__(256) void k_bhist(const int* __restrict__ ei,
                                               int* __restrict__ gcnt){
  __shared__ int lh[NBK];
  int t = threadIdx.x;
  for (int i = t; i < NBK; i += 256) lh[i] = 0;
  __syncthreads();
  int e = blockIdx.x*2048 + t;
  #pragma unroll
  for (int i = 0; i < 8; ++i, e += 256)
    if (e < EE) atomicAdd(&lh[ei[EE + e] >> 9], 1);
  __syncthreads();
  for (int i = t; i < NBK; i += 256)
    if (lh[i]) atomicAdd(&gcnt[i], lh[i]);
}

__global__ void k_bscan(const int* __restrict__ gcnt, int* __restrict__ bbase,
                        int* __restrict__ gcur, int* __restrict__ rowptr){
  __shared__ int ls[256];
  int t = threadIdx.x;
  int v = (t < NBK) ? gcnt[t] : 0;
  ls[t] = v; __syncthreads();
  #pragma unroll
  for (int off = 1; off < 256; off <<= 1){
    int x = (t >= off) ? ls[t-off] : 0;
    __syncthreads();
    ls[t] += x;
    __syncthreads();
  }
  int ex = ls[t] - v;
  if (t < NBK){ bbase[t] = ex; gcur[t] = ex; }
  if (t == NBK-1) bbase[NBK] = ex + v;   // == EE
  if (t == 0) rowptr[NN] = EE;
}

__global__ __launch_bounds__(256) void k_part(const int* __restrict__ ei,
                                              int* __restrict__ gcur,
                                              int2* __restrict__ pbuf){
  __shared__ int lh[NBK];
  __shared__ int lcur[NBK];
  int t = threadIdx.x;
  for (int i = t; i < NBK; i += 256) lh[i] = 0;
  __syncthreads();
  int e0 = blockIdx.x*2048;
  #pragma unroll
  for (int i = 0; i < 8; ++i){
    int e = e0 + i*256 + t;
    if (e < EE) atomicAdd(&lh[ei[EE + e] >> 9], 1);
  }
  __syncthreads();
  for (int i = t; i < NBK; i += 256)
    lcur[i] = lh[i] ? atomicAdd(&gcur[i], lh[i]) : 0;
  __syncthreads();
  #pragma unroll
  for (int i = 0; i < 8; ++i){
    int e = e0 + i*256 + t;
    if (e < EE){
      int s = ei[e], d = ei[EE + e];
      int pos = atomicAdd(&lcur[d >> 9], 1);
      pbuf[pos] = make_int2(s, d);
    }
  }
}

// one block per bucket: LDS hist + local scan + local-cursor fill
__global__ __launch_bounds__(256) void k_bfill(const int2* __restrict__ pbuf,
                                               const int* __restrict__ bbase,
                                               int* __restrict__ rowptr,
                                               int* __restrict__ esrc,
                                               float* __restrict__ dis){
  __shared__ int lcnt[BKT];
  __shared__ int ls[256];
  int b = blockIdx.x, t = threadIdx.x;
  int n0 = b*BKT;
  int e0 = bbase[b], e1 = bbase[b+1];
  lcnt[2*t] = 0; lcnt[2*t+1] = 0;
  __syncthreads();
  for (int e = e0 + t; e < e1; e += 256)
    atomicAdd(&lcnt[pbuf[e].y - n0], 1);
  __syncthreads();
  int v0 = lcnt[2*t], v1 = lcnt[2*t+1];
  int s = v0 + v1;
  ls[t] = s; __syncthreads();
  #pragma unroll
  for (int off = 1; off < 256; off <<= 1){
    int x = (t >= off) ? ls[t-off] : 0;
    __syncthreads();
    ls[t] += x;
    __syncthreads();
  }
  int run = ls[t] - s;                    // exclusive prefix (pairs)
  if (n0 + 2*t < NN){
    rowptr[n0 + 2*t] = e0 + run;
    dis[n0 + 2*t] = rsqrtf((float)v0 + 1.0f);
  }
  if (n0 + 2*t + 1 < NN){
    rowptr[n0 + 2*t + 1] = e0 + run + v0;
    dis[n0 + 2*t + 1] = rsqrtf((float)v1 + 1.0f);
  }
  lcnt[2*t] = run; lcnt[2*t+1] = run + v0;  // relative cursors
  __syncthreads();
  for (int e = e0 + t; e < e1; e += 256){
    int2 p = pbuf[e];
    int pos = atomicAdd(&lcnt[p.y - n0], 1);
    esrc[e0 + pos] = p.x;
  }
}

// ---------------- GEMM1: h1 = x @ W1, 64-row tile, 8x4 per thread -------------
__global__ __launch_bounds__(256) void k_gemm1(const float* __restrict__ x,
                                               const float* __restrict__ W1,
                                               float* __restrict__ h1){
  __shared__ float xs[64][IND];
  int t = threadIdx.x;
  int rbase = blockIdx.x * 64;
  #pragma unroll
  for (int i = 0; i < 8; ++i){
    int flat = i*256 + t;
    int r = flat >> 5;
    int q = flat & 31;
    float4 v = make_float4(0.f,0.f,0.f,0.f);
    if (rbase + r < NN) v = *(const float4*)&x[(size_t)(rbase+r)*IND + q*4];
    *(float4*)&xs[r][q*4] = v;
  }
  __syncthreads();
  int c0 = (t & 31) * 4;
  int r0 = (t >> 5) * 8;
  float acc[8][4] = {};
  #pragma unroll 4
  for (int k4 = 0; k4 < IND/4; ++k4){
    float4 w0 = *(const float4*)&W1[(k4*4+0)*HD + c0];
    float4 w1 = *(const float4*)&W1[(k4*4+1)*HD + c0];
    float4 w2 = *(const float4*)&W1[(k4*4+2)*HD + c0];
    float4 w3 = *(const float4*)&W1[(k4*4+3)*HD + c0];
    #pragma unroll
    for (int g = 0; g < 8; ++g){
      float4 xv = *(const float4*)&xs[r0+g][k4*4];
      acc[g][0] += xv.x*w0.x + xv.y*w1.x + xv.z*w2.x + xv.w*w3.x;
      acc[g][1] += xv.x*w0.y + xv.y*w1.y + xv.z*w2.y + xv.w*w3.y;
      acc[g][2] += xv.x*w0.z + xv.y*w1.z + xv.z*w2.z + xv.w*w3.z;
      acc[g][3] += xv.x*w0.w + xv.y*w1.w + xv.z*w2.w + xv.w*w3.w;
    }
  }
  #pragma unroll
  for (int g = 0; g < 8; ++g){
    int r = rbase + r0 + g;
    if (r < NN) *(float4*)&h1[(size_t)r*HD + c0] = *(float4*)&acc[g][0];
  }
}

// ---------------- GCN1 gather: 1 wave/node, 2 edges per iter ------------------
__global__ __launch_bounds__(256) void k_gather1(
    const int* __restrict__ rowptr, const int* __restrict__ esrc,
    const float* __restrict__ dis, const float* __restrict__ h1,
    const float* __restrict__ b1, float* __restrict__ hg){
  int w = threadIdx.x >> 6, lane = threadIdx.x & 63;
  int d = blockIdx.x*4 + w;
  int half = lane >> 5;
  int q = lane & 31;
  float dd = dis[d];
  float4 a = make_float4(0.f,0.f,0.f,0.f);
  if (half == 0){
    float4 v = *(const float4*)&h1[(size_t)d*HD + q*4];
    float s2 = dd*dd;
    a.x = v.x*s2; a.y = v.y*s2; a.z = v.z*s2; a.w = v.w*s2;
  }
  int p0 = rowptr[d], p1 = rowptr[d+1];
  for (int p = p0 + half; p < p1; p += 2){
    int s = esrc[p];
    float nm = dis[s]*dd;
    float4 v = *(const float4*)&h1[(size_t)s*HD + q*4];
    a.x += v.x*nm; a.y += v.y*nm; a.z += v.z*nm; a.w += v.w*nm;
  }
  a.x += __shfl_xor(a.x, 32); a.y += __shfl_xor(a.y, 32);
  a.z += __shfl_xor(a.z, 32); a.w += __shfl_xor(a.w, 32);
  if (half == 0){
    float4 b = *(const float4*)&b1[q*4];
    a.x += b.x; a.y += b.y; a.z += b.z; a.w += b.w;
    *(float4*)&hg[(size_t)d*HD + q*4] = a;
  }
}

// ---------------- BatchNorm stats + coefficients ----------------
__global__ void k_stats_zero(float* __restrict__ sums, float* __restrict__ sumsq){
  int i = threadIdx.x;
  if (i < HD){ sums[i] = 0.f; sumsq[i] = 0.f; }
}

__global__ void k_bn_stats(const float* __restrict__ hg, float* __restrict__ sums,
                           float* __restrict__ sumsq){
  int j = threadIdx.x;
  int r0 = blockIdx.x * BN_ROWS;
  int r1 = min(r0 + BN_ROWS, NN);
  float s = 0.f, q = 0.f;
  for (int r = r0; r < r1; ++r){
    float v = hg[(size_t)r*HD + j];
    s += v; q += v*v;
  }
  atomicAdd(&sums[j], s);
  atomicAdd(&sumsq[j], q);
}

__global__ void k_bn_coef(const float* __restrict__ sums, const float* __restrict__ sumsq,
                          const float* __restrict__ gamma, const float* __restrict__ beta,
                          float* __restrict__ scale, float* __restrict__ shift){
  int j = threadIdx.x;
  const float invN = 1.0f/(float)NN;
  float mu  = sums[j]*invN;
  float var = sumsq[j]*invN - mu*mu;
  float sc  = gamma[j]*rsqrtf(var+BN_EPS);
  scale[j] = sc;
  shift[j] = beta[j] - mu*sc;
}

// ---------------- GEMM2: h2 = relu(bn(hg)) @ W2 ----------------
__global__ __launch_bounds__(256) void k_gemm2(const float* __restrict__ hg,
                                               const float* __restrict__ W2,
                                               const float* __restrict__ scale,
                                               const float* __restrict__ shift,
                                               float* __restrict__ h2){
  __shared__ float hs[64][HD];
  int t = threadIdx.x;
  int rbase = blockIdx.x * 64;
  #pragma unroll
  for (int i = 0; i < 8; ++i){
    int flat = i*256 + t;
    int r = flat >> 5;
    int q = flat & 31;
    float4 v = make_float4(0.f,0.f,0.f,0.f);
    if (rbase + r < NN){
      v = *(const float4*)&hg[(size_t)(rbase+r)*HD + q*4];
      float4 sc = *(const float4*)&scale[q*4];
      float4 sh = *(const float4*)&shift[q*4];
      v.x = fmaxf(v.x*sc.x + sh.x, 0.f);
      v.y = fmaxf(v.y*sc.y + sh.y, 0.f);
      v.z = fmaxf(v.z*sc.z + sh.z, 0.f);
      v.w = fmaxf(v.w*sc.w + sh.w, 0.f);
    }
    *(float4*)&hs[r][q*4] = v;
  }
  __syncthreads();
  int c0 = (t & 15) * 4;
  int r0 = (t >> 4) * 4;
  float acc[4][4] = {};
  #pragma unroll 4
  for (int k4 = 0; k4 < HD/4; ++k4){
    float4 w0 = *(const float4*)&W2[(k4*4+0)*EM + c0];
    float4 w1 = *(const float4*)&W2[(k4*4+1)*EM + c0];
    float4 w2 = *(const float4*)&W2[(k4*4+2)*EM + c0];
    float4 w3 = *(const float4*)&W2[(k4*4+3)*EM + c0];
    #pragma unroll
    for (int g = 0; g < 4; ++g){
      float4 xv = *(const float4*)&hs[r0+g][k4*4];
      acc[g][0] += xv.x*w0.x + xv.y*w1.x + xv.z*w2.x + xv.w*w3.x;
      acc[g][1] += xv.x*w0.y + xv.y*w1.y + xv.z*w2.y + xv.w*w3.y;
      acc[g][2] += xv.x*w0.z + xv.y*w1.z + xv.z*w2.z + xv.w*w3.z;
      acc[g][3] += xv.x*w0.w + xv.y*w1.w + xv.z*w2.w + xv.w*w3.w;
    }
  }
  #pragma unroll
  for (int g = 0; g < 4; ++g){
    int r = rbase + r0 + g;
    if (r < NN) *(float4*)&h2[(size_t)r*EM + c0] = *(float4*)&acc[g][0];
  }
}

// ---------------- GCN2 gather + bias + emb out ----------------
__global__ __launch_bounds__(256) void k_gather2(
    const int* __restrict__ rowptr, const int* __restrict__ esrc,
    const float* __restrict__ dis, const float* __restrict__ h2,
    const float* __restrict__ b2v, float* __restrict__ embf,
    float* __restrict__ out){
  int w = threadIdx.x >> 6, lane = threadIdx.x & 63;
  int d = blockIdx.x*4 + w;
  int sub = lane >> 4;
  int q = lane & 15;
  float dd = dis[d];
  float4 a = make_float4(0.f,0.f,0.f,0.f);
  if (sub == 0){
    float4 v = *(const float4*)&h2[(size_t)d*EM + q*4];
    float s2 = dd*dd;
    a.x = v.x*s2; a.y = v.y*s2; a.z = v.z*s2; a.w = v.w*s2;
  }
  int p0 = rowptr[d], p1 = rowptr[d+1];
  for (int p = p0 + sub; p < p1; p += 4){
    int s = esrc[p];
    float nm = dis[s]*dd;
    float4 v = *(const float4*)&h2[(size_t)s*EM + q*4];
    a.x += v.x*nm; a.y += v.y*nm; a.z += v.z*nm; a.w += v.w*nm;
  }
  a.x += __shfl_xor(a.x, 32); a.y += __shfl_xor(a.y, 32);
  a.z += __shfl_xor(a.z, 32); a.w += __shfl_xor(a.w, 32);
  a.x += __shfl_xor(a.x, 16); a.y += __shfl_xor(a.y, 16);
  a.z += __shfl_xor(a.z, 16); a.w += __shfl_xor(a.w, 16);
  if (sub == 0){
    float4 b = *(const float4*)&b2v[q*4];
    a.x += b.x; a.y += b.y; a.z += b.z; a.w += b.w;
    *(float4*)&embf[(size_t)d*EM + q*4] = a;
    *(float4*)&out [(size_t)d*EM + q*4] = a;
  }
}

// ---------------- logits + softmax: centers in registers, 32 rows/block -------
__global__ __launch_bounds__(256) void k_softmax(const float* __restrict__ embf,
                          const float* __restrict__ centers,
                          const float* __restrict__ temp,
                          float* __restrict__ out){
  __shared__ float er[SROWS][EM];        // 8 KB
  int t = threadIdx.x, w = t >> 6, lane = t & 63;
  int rbase = blockIdx.x * SROWS;        // NN % 32 == 0
  #pragma unroll
  for (int i = 0; i < 2; ++i){
    int flat = (i*256 + t)*4;
    int r = flat >> 6, c = flat & 63;
    *(float4*)&er[r][c] = *(const float4*)&embf[(size_t)(rbase+r)*EM + c];
  }
  int c0 = lane;
  int c1 = (lane < KC-64) ? lane + 64 : KC-1;
  float4 rc0[16], rc1[16];
  #pragma unroll
  for (int k4 = 0; k4 < 16; ++k4){
    rc0[k4] = *(const float4*)&centers[c0*EM + k4*4];
    rc1[k4] = *(const float4*)&centers[c1*EM + k4*4];
  }
  __syncthreads();
  float acc0[8] = {}, acc1[8] = {};
  #pragma unroll
  for (int k4 = 0; k4 < 16; ++k4){
    float4 a0 = rc0[k4], a1 = rc1[k4];
    #pragma unroll
    for (int r = 0; r < 8; ++r){
      float4 ev = *(const float4*)&er[w*8 + r][k4*4];
      acc0[r] += ev.x*a0.x + ev.y*a0.y + ev.z*a0.z + ev.w*a0.w;
      acc1[r] += ev.x*a1.x + ev.y*a1.y + ev.z*a1.z + ev.w*a1.w;
    }
  }
  float invT = 1.0f / temp[0];
  #pragma unroll
  for (int r = 0; r < 8; ++r){
    float lg0 = acc0[r] * invT;
    float lg1 = (lane < KC-64) ? acc1[r] * invT : -1e30f;
    float m = fmaxf(lg0, lg1);
    #pragma unroll
    for (int off = 32; off > 0; off >>= 1) m = fmaxf(m, __shfl_xor(m, off));
    float e0 = __expf(lg0 - m);
    float e1 = (lane < KC-64) ? __expf(lg1 - m) : 0.f;
    float ssum = e0 + e1;
    #pragma unroll
    for (int off = 32; off > 0; off >>= 1) ssum += __shfl_xor(ssum, off);
    float inv = 1.0f / ssum;
    int row = rbase + w*8 + r;
    float* orow = out + (size_t)NN*EM + (size_t)row*KC;
    orow[lane] = e0 * inv;
    if (lane < KC-64) orow[64 + lane] = e1 * inv;
  }
}

// ---------------- launch ----------------
extern "C" void kernel_launch(void* const* d_in, const int* in_sizes, int n_in,
                              void* d_out, int out_size, void* d_ws, size_t ws_size,
                              hipStream_t stream){
  const float* x      = (const float*)d_in[0];
  const int*   ei     = (const int*)d_in[1];
  const float* W1     = (const float*)d_in[2];
  const float* b1     = (const float*)d_in[3];
  const float* gamma  = (const float*)d_in[4];
  const float* beta   = (const float*)d_in[5];
  const float* W2     = (const float*)d_in[6];
  const float* b2v    = (const float*)d_in[7];
  const float* ctr    = (const float*)d_in[8];
  const float* temp   = (const float*)d_in[9];
  float* out = (float*)d_out;

  // ws: dis[NN] | bufA[NN*HD] | bufB[NN*HD] | sums,sumsq,scale,shift[HD] |
  //     rowptr[NN+1] | esrc[EE] | gcnt[256] bbase[257] gcur[256]
  // pbuf (int2[EE]) overlays bufB (dead until gather1 writes hg).
  float* ws     = (float*)d_ws;
  float* dis    = ws;
  float* bufA   = dis + NN;
  float* bufB   = bufA + (size_t)NN*HD;
  float* sums   = bufB + (size_t)NN*HD;
  float* sumsq  = sums + HD;
  float* scale  = sumsq + HD;
  float* shift  = scale + HD;
  int*   rowptr = (int*)(shift + HD);
  int*   esrc   = rowptr + NN + 1;
  int*   gcnt   = esrc + EE;
  int*   bbase  = gcnt + 256;
  int*   gcur   = bbase + 257;
  int2*  pbuf   = (int2*)bufB;

  float* h1   = bufA;
  float* hg   = bufB;
  float* h2   = bufA;
  float* embf = bufA + (size_t)NN*EM;

  k_zero256<<<1, 256, 0, stream>>>(gcnt);
  k_bhist  <<<(EE+2047)/2048, 256, 0, stream>>>(ei, gcnt);
  k_bscan  <<<1, 256, 0, stream>>>(gcnt, bbase, gcur, rowptr);
  k_part   <<<(EE+2047)/2048, 256, 0, stream>>>(ei, gcur, pbuf);
  k_bfill  <<<NBK, 256, 0, stream>>>(pbuf, bbase, rowptr, esrc, dis);

  k_gemm1  <<<(NN+63)/64, 256, 0, stream>>>(x, W1, h1);
  k_gather1<<<NN/4, 256, 0, stream>>>(rowptr, esrc, dis, h1, b1, hg);

  k_stats_zero<<<1, 128, 0, stream>>>(sums, sumsq);
  k_bn_stats<<<(NN+BN_ROWS-1)/BN_ROWS, 128, 0, stream>>>(hg, sums, sumsq);
  k_bn_coef <<<1, 128, 0, stream>>>(sums, sumsq, gamma, beta, scale, shift);

  k_gemm2  <<<(NN+63)/64, 256, 0, stream>>>(hg, W2, scale, shift, h2);
  k_gather2<<<NN/4, 256, 0, stream>>>(rowptr, esrc, dis, h2, b2v, embf, out);

  k_softmax<<<NN/SROWS, 256, 0, stream>>>(embf, ctr, temp, out);
}

// Round 6
// 629.660 us; speedup vs baseline: 2.8001x; 1.1985x over previous
//
#include <hip/hip_runtime.h>
#include <hip/hip_bf16.h>

#define NN 100000
#define EE 1600000
#define IND 128
#define HD 128
#define EM 64
#define KC 100
#define BN_EPS 1e-5f
#define BN_ROWS 128
#define BKT 512
#define NBK ((NN + BKT - 1) / BKT)      // 196 buckets (dst >> 9)
#define SROWS 32                         // softmax rows per block

// ---------------- bucketed CSR build ----------------
__global__ void k_zero256(int* __restrict__ gcnt){
  int t = threadIdx.x;
  if (t < NBK) gcnt[t] = 0;
}

__global__ __launch_bounds__(256) void k_bhist(const int* __restrict__ ei,
                                               int* __restrict__ gcnt){
  __shared__ int lh[NBK];
  int t = threadIdx.x;
  for (int i = t; i < NBK; i += 256) lh[i] = 0;
  __syncthreads();
  int e = blockIdx.x*2048 + t;
  #pragma unroll
  for (int i = 0; i < 8; ++i, e += 256)
    if (e < EE) atomicAdd(&lh[ei[EE + e] >> 9], 1);
  __syncthreads();
  for (int i = t; i < NBK; i += 256)
    if (lh[i]) atomicAdd(&gcnt[i], lh[i]);
}

__global__ void k_bscan(const int* __restrict__ gcnt, int* __restrict__ bbase,
                        int* __restrict__ gcur, int* __restrict__ rowptr){
  __shared__ int ls[256];
  int t = threadIdx.x;
  int v = (t < NBK) ? gcnt[t] : 0;
  ls[t] = v; __syncthreads();
  #pragma unroll
  for (int off = 1; off < 256; off <<= 1){
    int x = (t >= off) ? ls[t-off] : 0;
    __syncthreads();
    ls[t] += x;
    __syncthreads();
  }
  int ex = ls[t] - v;
  if (t < NBK){ bbase[t] = ex; gcur[t] = ex; }
  if (t == NBK-1) bbase[NBK] = ex + v;   // == EE
  if (t == 0) rowptr[NN] = EE;
}

__global__ __launch_bounds__(256) void k_part(const int* __restrict__ ei,
                                              int* __restrict__ gcur,
                                              int2* __restrict__ pbuf){
  __shared__ int lh[NBK];
  __shared__ int lcur[NBK];
  int t = threadIdx.x;
  for (int i = t; i < NBK; i += 256) lh[i] = 0;
  __syncthreads();
  int e0 = blockIdx.x*2048;
  #pragma unroll
  for (int i = 0; i < 8; ++i){
    int e = e0 + i*256 + t;
    if (e < EE) atomicAdd(&lh[ei[EE + e] >> 9], 1);
  }
  __syncthreads();
  for (int i = t; i < NBK; i += 256)
    lcur[i] = lh[i] ? atomicAdd(&gcur[i], lh[i]) : 0;
  __syncthreads();
  #pragma unroll
  for (int i = 0; i < 8; ++i){
    int e = e0 + i*256 + t;
    if (e < EE){
      int s = ei[e], d = ei[EE + e];
      int pos = atomicAdd(&lcur[d >> 9], 1);
      pbuf[pos] = make_int2(s, d);
    }
  }
}

// one block per bucket: LDS hist + local scan + local-cursor fill
__global__ __launch_bounds__(256) void k_bfill(const int2* __restrict__ pbuf,
                                               const int* __restrict__ bbase,
                                               int* __restrict__ rowptr,
                                               int* __restrict__ esrc,
                                               float* __restrict__ dis){
  __shared__ int lcnt[BKT];
  __shared__ int ls[256];
  int b = blockIdx.x, t = threadIdx.x;
  int n0 = b*BKT;
  int e0 = bbase[b], e1 = bbase[b+1];
  lcnt[2*t] = 0; lcnt[2*t+1] = 0;
  __syncthreads();
  for (int e = e0 + t; e < e1; e += 256)
    atomicAdd(&lcnt[pbuf[e].y - n0], 1);
  __syncthreads();
  int v0 = lcnt[2*t], v1 = lcnt[2*t+1];
  int s = v0 + v1;
  ls[t] = s; __syncthreads();
  #pragma unroll
  for (int off = 1; off < 256; off <<= 1){
    int x = (t >= off) ? ls[t-off] : 0;
    __syncthreads();
    ls[t] += x;
    __syncthreads();
  }
  int run = ls[t] - s;                    // exclusive prefix (pairs)
  if (n0 + 2*t < NN){
    rowptr[n0 + 2*t] = e0 + run;
    dis[n0 + 2*t] = rsqrtf((float)v0 + 1.0f);
  }
  if (n0 + 2*t + 1 < NN){
    rowptr[n0 + 2*t + 1] = e0 + run + v0;
    dis[n0 + 2*t + 1] = rsqrtf((float)v1 + 1.0f);
  }
  lcnt[2*t] = run; lcnt[2*t+1] = run + v0;  // relative cursors
  __syncthreads();
  for (int e = e0 + t; e < e1; e += 256){
    int2 p = pbuf[e];
    int pos = atomicAdd(&lcnt[p.y - n0], 1);
    esrc[e0 + pos] = p.x;
  }
}

// ---------------- GEMM1: h1 = x @ W1, 64-row tile, 8x4 per thread -------------
__global__ __launch_bounds__(256) void k_gemm1(const float* __restrict__ x,
                                               const float* __restrict__ W1,
                                               float* __restrict__ h1){
  __shared__ float xs[64][IND];
  int t = threadIdx.x;
  int rbase = blockIdx.x * 64;
  #pragma unroll
  for (int i = 0; i < 8; ++i){
    int flat = i*256 + t;
    int r = flat >> 5;
    int q = flat & 31;
    float4 v = make_float4(0.f,0.f,0.f,0.f);
    if (rbase + r < NN) v = *(const float4*)&x[(size_t)(rbase+r)*IND + q*4];
    *(float4*)&xs[r][q*4] = v;
  }
  __syncthreads();
  int c0 = (t & 31) * 4;
  int r0 = (t >> 5) * 8;
  float acc[8][4] = {};
  #pragma unroll 4
  for (int k4 = 0; k4 < IND/4; ++k4){
    float4 w0 = *(const float4*)&W1[(k4*4+0)*HD + c0];
    float4 w1 = *(const float4*)&W1[(k4*4+1)*HD + c0];
    float4 w2 = *(const float4*)&W1[(k4*4+2)*HD + c0];
    float4 w3 = *(const float4*)&W1[(k4*4+3)*HD + c0];
    #pragma unroll
    for (int g = 0; g < 8; ++g){
      float4 xv = *(const float4*)&xs[r0+g][k4*4];
      acc[g][0] += xv.x*w0.x + xv.y*w1.x + xv.z*w2.x + xv.w*w3.x;
      acc[g][1] += xv.x*w0.y + xv.y*w1.y + xv.z*w2.y + xv.w*w3.y;
      acc[g][2] += xv.x*w0.z + xv.y*w1.z + xv.z*w2.z + xv.w*w3.z;
      acc[g][3] += xv.x*w0.w + xv.y*w1.w + xv.z*w2.w + xv.w*w3.w;
    }
  }
  #pragma unroll
  for (int g = 0; g < 8; ++g){
    int r = rbase + r0 + g;
    if (r < NN) *(float4*)&h1[(size_t)r*HD + c0] = *(float4*)&acc[g][0];
  }
}

// ---------------- GCN1 gather: 1 wave/node, 2 edges per iter ------------------
__global__ __launch_bounds__(256) void k_gather1(
    const int* __restrict__ rowptr, const int* __restrict__ esrc,
    const float* __restrict__ dis, const float* __restrict__ h1,
    const float* __restrict__ b1, float* __restrict__ hg){
  int w = threadIdx.x >> 6, lane = threadIdx.x & 63;
  int d = blockIdx.x*4 + w;
  int half = lane >> 5;
  int q = lane & 31;
  float dd = dis[d];
  float4 a = make_float4(0.f,0.f,0.f,0.f);
  if (half == 0){
    float4 v = *(const float4*)&h1[(size_t)d*HD + q*4];
    float s2 = dd*dd;
    a.x = v.x*s2; a.y = v.y*s2; a.z = v.z*s2; a.w = v.w*s2;
  }
  int p0 = rowptr[d], p1 = rowptr[d+1];
  for (int p = p0 + half; p < p1; p += 2){
    int s = esrc[p];
    float nm = dis[s]*dd;
    float4 v = *(const float4*)&h1[(size_t)s*HD + q*4];
    a.x += v.x*nm; a.y += v.y*nm; a.z += v.z*nm; a.w += v.w*nm;
  }
  a.x += __shfl_xor(a.x, 32); a.y += __shfl_xor(a.y, 32);
  a.z += __shfl_xor(a.z, 32); a.w += __shfl_xor(a.w, 32);
  if (half == 0){
    float4 b = *(const float4*)&b1[q*4];
    a.x += b.x; a.y += b.y; a.z += b.z; a.w += b.w;
    *(float4*)&hg[(size_t)d*HD + q*4] = a;
  }
}

// ---------------- BatchNorm stats + coefficients ----------------
__global__ void k_stats_zero(float* __restrict__ sums, float* __restrict__ sumsq){
  int i = threadIdx.x;
  if (i < HD){ sums[i] = 0.f; sumsq[i] = 0.f; }
}

__global__ void k_bn_stats(const float* __restrict__ hg, float* __restrict__ sums,
                           float* __restrict__ sumsq){
  int j = threadIdx.x;
  int r0 = blockIdx.x * BN_ROWS;
  int r1 = min(r0 + BN_ROWS, NN);
  float s = 0.f, q = 0.f;
  for (int r = r0; r < r1; ++r){
    float v = hg[(size_t)r*HD + j];
    s += v; q += v*v;
  }
  atomicAdd(&sums[j], s);
  atomicAdd(&sumsq[j], q);
}

__global__ void k_bn_coef(const float* __restrict__ sums, const float* __restrict__ sumsq,
                          const float* __restrict__ gamma, const float* __restrict__ beta,
                          float* __restrict__ scale, float* __restrict__ shift){
  int j = threadIdx.x;
  const float invN = 1.0f/(float)NN;
  float mu  = sums[j]*invN;
  float var = sumsq[j]*invN - mu*mu;
  float sc  = gamma[j]*rsqrtf(var+BN_EPS);
  scale[j] = sc;
  shift[j] = beta[j] - mu*sc;
}

// ---------------- GEMM2: h2 = relu(bn(hg)) @ W2 ----------------
__global__ __launch_bounds__(256) void k_gemm2(const float* __restrict__ hg,
                                               const float* __restrict__ W2,
                                               const float* __restrict__ scale,
                                               const float* __restrict__ shift,
                                               float* __restrict__ h2){
  __shared__ float hs[64][HD];
  int t = threadIdx.x;
  int rbase = blockIdx.x * 64;
  #pragma unroll
  for (int i = 0; i < 8; ++i){
    int flat = i*256 + t;
    int r = flat >> 5;
    int q = flat & 31;
    float4 v = make_float4(0.f,0.f,0.f,0.f);
    if (rbase + r < NN){
      v = *(const float4*)&hg[(size_t)(rbase+r)*HD + q*4];
      float4 sc = *(const float4*)&scale[q*4];
      float4 sh = *(const float4*)&shift[q*4];
      v.x = fmaxf(v.x*sc.x + sh.x, 0.f);
      v.y = fmaxf(v.y*sc.y + sh.y, 0.f);
      v.z = fmaxf(v.z*sc.z + sh.z, 0.f);
      v.w = fmaxf(v.w*sc.w + sh.w, 0.f);
    }
    *(float4*)&hs[r][q*4] = v;
  }
  __syncthreads();
  int c0 = (t & 15) * 4;
  int r0 = (t >> 4) * 4;
  float acc[4][4] = {};
  #pragma unroll 4
  for (int k4 = 0; k4 < HD/4; ++k4){
    float4 w0 = *(const float4*)&W2[(k4*4+0)*EM + c0];
    float4 w1 = *(const float4*)&W2[(k4*4+1)*EM + c0];
    float4 w2 = *(const float4*)&W2[(k4*4+2)*EM + c0];
    float4 w3 = *(const float4*)&W2[(k4*4+3)*EM + c0];
    #pragma unroll
    for (int g = 0; g < 4; ++g){
      float4 xv = *(const float4*)&hs[r0+g][k4*4];
      acc[g][0] += xv.x*w0.x + xv.y*w1.x + xv.z*w2.x + xv.w*w3.x;
      acc[g][1] += xv.x*w0.y + xv.y*w1.y + xv.z*w2.y + xv.w*w3.y;
      acc[g][2] += xv.x*w0.z + xv.y*w1.z + xv.z*w2.z + xv.w*w3.z;
      acc[g][3] += xv.x*w0.w + xv.y*w1.w + xv.z*w2.w + xv.w*w3.w;
    }
  }
  #pragma unroll
  for (int g = 0; g < 4; ++g){
    int r = rbase + r0 + g;
    if (r < NN) *(float4*)&h2[(size_t)r*EM + c0] = *(float4*)&acc[g][0];
  }
}

// ---------------- GCN2 gather + bias + emb out ----------------
__global__ __launch_bounds__(256) void k_gather2(
    const int* __restrict__ rowptr, const int* __restrict__ esrc,
    const float* __restrict__ dis, const float* __restrict__ h2,
    const float* __restrict__ b2v, float* __restrict__ embf,
    float* __restrict__ out){
  int w = threadIdx.x >> 6, lane = threadIdx.x & 63;
  int d = blockIdx.x*4 + w;
  int sub = lane >> 4;
  int q = lane & 15;
  float dd = dis[d];
  float4 a = make_float4(0.f,0.f,0.f,0.f);
  if (sub == 0){
    float4 v = *(const float4*)&h2[(size_t)d*EM + q*4];
    float s2 = dd*dd;
    a.x = v.x*s2; a.y = v.y*s2; a.z = v.z*s2; a.w = v.w*s2;
  }
  int p0 = rowptr[d], p1 = rowptr[d+1];
  for (int p = p0 + sub; p < p1; p += 4){
    int s = esrc[p];
    float nm = dis[s]*dd;
    float4 v = *(const float4*)&h2[(size_t)s*EM + q*4];
    a.x += v.x*nm; a.y += v.y*nm; a.z += v.z*nm; a.w += v.w*nm;
  }
  a.x += __shfl_xor(a.x, 32); a.y += __shfl_xor(a.y, 32);
  a.z += __shfl_xor(a.z, 32); a.w += __shfl_xor(a.w, 32);
  a.x += __shfl_xor(a.x, 16); a.y += __shfl_xor(a.y, 16);
  a.z += __shfl_xor(a.z, 16); a.w += __shfl_xor(a.w, 16);
  if (sub == 0){
    float4 b = *(const float4*)&b2v[q*4];
    a.x += b.x; a.y += b.y; a.z += b.z; a.w += b.w;
    *(float4*)&embf[(size_t)d*EM + q*4] = a;
    *(float4*)&out [(size_t)d*EM + q*4] = a;
  }
}

// ---- logits + softmax: 32 rows/block, centers streamed from L1, 8 rows/wave --
__global__ __launch_bounds__(256, 4) void k_softmax(const float* __restrict__ embf,
                          const float* __restrict__ centers,
                          const float* __restrict__ temp,
                          float* __restrict__ out){
  __shared__ float er[SROWS][EM];        // 8 KB
  int t = threadIdx.x, w = t >> 6, lane = t & 63;
  int rbase = blockIdx.x * SROWS;        // NN % 32 == 0
  #pragma unroll
  for (int i = 0; i < 2; ++i){
    int flat = (i*256 + t)*4;
    int r = flat >> 6, c = flat & 63;
    *(float4*)&er[r][c] = *(const float4*)&embf[(size_t)(rbase+r)*EM + c];
  }
  __syncthreads();
  int c0 = lane;
  int c1 = (lane < KC-64) ? lane + 64 : KC-1;
  const float* C0 = centers + c0*EM;     // 25.6 KB total -> L1-resident
  const float* C1 = centers + c1*EM;
  float acc0[8] = {}, acc1[8] = {};
  #pragma unroll 4
  for (int k4 = 0; k4 < 16; ++k4){
    float4 a0 = *(const float4*)&C0[k4*4];
    float4 a1 = *(const float4*)&C1[k4*4];
    #pragma unroll
    for (int r = 0; r < 8; ++r){
      float4 ev = *(const float4*)&er[w*8 + r][k4*4];   // broadcast ds_read
      acc0[r] += ev.x*a0.x + ev.y*a0.y + ev.z*a0.z + ev.w*a0.w;
      acc1[r] += ev.x*a1.x + ev.y*a1.y + ev.z*a1.z + ev.w*a1.w;
    }
  }
  float invT = 1.0f / temp[0];
  #pragma unroll
  for (int r = 0; r < 8; ++r){
    float lg0 = acc0[r] * invT;
    float lg1 = (lane < KC-64) ? acc1[r] * invT : -1e30f;
    float m = fmaxf(lg0, lg1);
    #pragma unroll
    for (int off = 32; off > 0; off >>= 1) m = fmaxf(m, __shfl_xor(m, off));
    float e0 = __expf(lg0 - m);
    float e1 = (lane < KC-64) ? __expf(lg1 - m) : 0.f;
    float ssum = e0 + e1;
    #pragma unroll
    for (int off = 32; off > 0; off >>= 1) ssum += __shfl_xor(ssum, off);
    float inv = 1.0f / ssum;
    int row = rbase + w*8 + r;
    float* orow = out + (size_t)NN*EM + (size_t)row*KC;
    orow[lane] = e0 * inv;
    if (lane < KC-64) orow[64 + lane] = e1 * inv;
  }
}

// ---------------- launch ----------------
extern "C" void kernel_launch(void* const* d_in, const int* in_sizes, int n_in,
                              void* d_out, int out_size, void* d_ws, size_t ws_size,
                              hipStream_t stream){
  const float* x      = (const float*)d_in[0];
  const int*   ei     = (const int*)d_in[1];
  const float* W1     = (const float*)d_in[2];
  const float* b1     = (const float*)d_in[3];
  const float* gamma  = (const float*)d_in[4];
  const float* beta   = (const float*)d_in[5];
  const float* W2     = (const float*)d_in[6];
  const float* b2v    = (const float*)d_in[7];
  const float* ctr    = (const float*)d_in[8];
  const float* temp   = (const float*)d_in[9];
  float* out = (float*)d_out;

  // ws: dis[NN] | bufA[NN*HD] | bufB[NN*HD] | sums,sumsq,scale,shift[HD] |
  //     rowptr[NN+1] | esrc[EE] | gcnt[256] bbase[257] gcur[256]
  // pbuf (int2[EE]) overlays bufB (dead until gather1 writes hg).
  float* ws     = (float*)d_ws;
  float* dis    = ws;
  float* bufA   = dis + NN;
  float* bufB   = bufA + (size_t)NN*HD;
  float* sums   = bufB + (size_t)NN*HD;
  float* sumsq  = sums + HD;
  float* scale  = sumsq + HD;
  float* shift  = scale + HD;
  int*   rowptr = (int*)(shift + HD);
  int*   esrc   = rowptr + NN + 1;
  int*   gcnt   = esrc + EE;
  int*   bbase  = gcnt + 256;
  int*   gcur   = bbase + 257;
  int2*  pbuf   = (int2*)bufB;

  float* h1   = bufA;
  float* hg   = bufB;
  float* h2   = bufA;
  float* embf = bufA + (size_t)NN*EM;

  k_zero256<<<1, 256, 0, stream>>>(gcnt);
  k_bhist  <<<(EE+2047)/2048, 256, 0, stream>>>(ei, gcnt);
  k_bscan  <<<1, 256, 0, stream>>>(gcnt, bbase, gcur, rowptr);
  k_part   <<<(EE+2047)/2048, 256, 0, stream>>>(ei, gcur, pbuf);
  k_bfill  <<<NBK, 256, 0, stream>>>(pbuf, bbase, rowptr, esrc, dis);

  k_gemm1  <<<(NN+63)/64, 256, 0, stream>>>(x, W1, h1);
  k_gather1<<<NN/4, 256, 0, stream>>>(rowptr, esrc, dis, h1, b1, hg);

  k_stats_zero<<<1, 128, 0, stream>>>(sums, sumsq);
  k_bn_stats<<<(NN+BN_ROWS-1)/BN_ROWS, 128, 0, stream>>>(hg, sums, sumsq);
  k_bn_coef <<<1, 128, 0, stream>>>(sums, sumsq, gamma, beta, scale, shift);

  k_gemm2  <<<(NN+63)/64, 256, 0, stream>>>(hg, W2, scale, shift, h2);
  k_gather2<<<NN/4, 256, 0, stream>>>(rowptr, esrc, dis, h2, b2v, embf, out);

  k_softmax<<<NN/SROWS, 256, 0, stream>>>(embf, ctr, temp, out);
}